// Round 5
// baseline (1437.275 us; speedup 1.0000x reference)
//
#include <hip/hip_runtime.h>
#include <hip/hip_fp16.h>
#include <cstdint>
#include <cstddef>

// KNN regressor, MFMA edition v5 — barrier-free K-loop, register-space filter.
//   score[n] = tsq[n] - 2*dot(q, x_n)
// dot via 2-pass fp16 split: q = qh + qr, x ~ xh;  dot ≈ qh·xh + qr·xh.
// Selection: per-(wave,q) LDS candidate buffers, shared monotone thresholds,
// drop-dead + bitonic compaction. Per-chunk exact top-32 (vs approx score) ->
// merge 8 chunks -> approx top-40 -> EXACT fp32 rescore -> top-32 -> mean(y).
//
// MFMA 16x16x32 f16 layouts (HW-verified, learn_hip m89/m91/m120):
//   A[m][k]: m = lane&15, k = (lane>>4)*8 + j
//   B[k][n]: n = lane&15, k = (lane>>4)*8 + j
//   C[m][n]: n(col) = lane&15, m(row) = (lane>>4)*4 + reg
//
// Xs swizzle: segment s = (n>>4)*4 + ks holds, at half8-index s*64 + L,
// Xh[row=(n&~15)+(L&15)][k=ks*32+(L>>4)*8 .. +8]  (1 KB per segment).

constexpr int Q_  = 4096;
constexpr int N_  = 100000;
constexpr int D_  = 128;
constexpr int K_  = 32;

constexpr int QT    = 32;            // queries per block
constexpr int BN    = 256;           // n per iteration
constexpr int NCH   = 8;             // chunks (ch = blockIdx.x & 7, XCD-affine)
constexpr int CHUNK = 12544;         // 49*256
constexpr int ITERS = CHUNK / BN;    // 49
constexpr int NPAD  = NCH * CHUNK;   // 100352
constexpr int CW    = 64;            // per-(wave,q) candidate buffer capacity
constexpr int KKEEP = 32;            // kept per compaction (per-chunk top-32)
constexpr int CTRIG = 56;            // compact when cnt exceeds this
constexpr int MKEEP = 40;            // global approx top kept for exact rescore

typedef __attribute__((ext_vector_type(8))) _Float16 half8;
typedef __attribute__((ext_vector_type(4))) float    floatx4;
typedef unsigned long long ull;

#define DEV __device__ __forceinline__
constexpr ull DEADC = ~0ull;

DEV ull pack_cand(float score, unsigned int n) {
    unsigned int s = __float_as_uint(score);
    s = (s & 0x80000000u) ? ~s : (s | 0x80000000u);   // monotone u32 key
    return ((ull)s << 32) | (ull)n;
}
DEV float unpack_score(ull k) {
    unsigned int s = (unsigned int)(k >> 32);
    s = (s & 0x80000000u) ? (s ^ 0x80000000u) : ~s;
    return __uint_as_float(s);
}
DEV ull u64min(ull a, ull b) { return a < b ? a : b; }
DEV float inf_f() { return __int_as_float(0x7f800000); }

// wave64 bitonic sort, ascending (DEADC sinks to the end)
DEV ull bitonic64(ull v, int L) {
    #pragma unroll
    for (int k2 = 2; k2 <= 64; k2 <<= 1)
        #pragma unroll
        for (int j2 = k2 >> 1; j2 >= 1; j2 >>= 1) {
            ull o = __shfl_xor(v, j2);
            bool up = ((L & k2) == 0);
            bool lo = ((L & j2) == 0);
            ull mn = u64min(v, o), mx = v ^ o ^ mn;
            v = (lo == up) ? mn : mx;
        }
    return v;
}

// ---------------------------------------------------------------- prep ------
__global__ void prep_xs(const float* __restrict__ X, __half* __restrict__ Xs,
                        float* __restrict__ tsq) {
    int L   = threadIdx.x & 63;
    int t16 = blockIdx.x * 4 + (threadIdx.x >> 6);   // 16-row tile
    int am = L & 15, aq = L >> 4;
    int r = t16 * 16 + am;
    float ssq = 0.f;
    #pragma unroll
    for (int ks = 0; ks < 4; ++ks) {
        int c = ks * 32 + aq * 8;
        float4 a = {0.f,0.f,0.f,0.f}, b = {0.f,0.f,0.f,0.f};
        if (r < N_) {
            a = *(const float4*)(X + (size_t)r * D_ + c);
            b = *(const float4*)(X + (size_t)r * D_ + c + 4);
        }
        half8 h;
        h[0] = (_Float16)a.x; h[1] = (_Float16)a.y;
        h[2] = (_Float16)a.z; h[3] = (_Float16)a.w;
        h[4] = (_Float16)b.x; h[5] = (_Float16)b.y;
        h[6] = (_Float16)b.z; h[7] = (_Float16)b.w;
        *(half8*)(Xs + ((size_t)(t16 * 4 + ks)) * 512 + L * 8) = h;
        ssq += a.x*a.x + a.y*a.y + a.z*a.z + a.w*a.w
             + b.x*b.x + b.y*b.y + b.z*b.z + b.w*b.w;
    }
    ssq += __shfl_xor(ssq, 16);
    ssq += __shfl_xor(ssq, 32);
    if (aq == 0) tsq[r] = (r < N_) ? ssq : inf_f();
}

__global__ void prep_q(const float* __restrict__ Qm, __half* __restrict__ Qh,
                       __half* __restrict__ Qr) {
    int L = threadIdx.x & 63;
    int r = blockIdx.x * 4 + (threadIdx.x >> 6);
    float2 x = *(const float2*)(Qm + (size_t)r * D_ + 2 * L);
    __half h0 = __float2half(x.x), h1 = __float2half(x.y);
    size_t o = (size_t)r * D_ + 2 * L;
    Qh[o] = h0; Qh[o + 1] = h1;
    Qr[o]     = __float2half(x.x - __half2float(h0));
    Qr[o + 1] = __float2half(x.y - __half2float(h1));
}

// ------------------------------------------------------------- main ---------
__global__ __launch_bounds__(256, 2) void knn_main(
    const __half* __restrict__ Qh, const __half* __restrict__ Qr,
    const __half* __restrict__ Xs, const float* __restrict__ tsq,
    ull* __restrict__ candOut)
{
    __shared__ ull   cand[4][QT][CW];     // 64 KB, wave-private buffers
    __shared__ float thrF[QT];            // shared thresholds (monotone-safe)
    __shared__ int   cnt[4][QT];
    // LDS ~66 KB -> 2 blocks/CU

    const int tid = threadIdx.x;
    const int L   = tid & 63;
    const int wv  = tid >> 6;
    const int lb  = blockIdx.x;
    const int ch  = lb & 7;                           // XCD-affine chunk
    const int qbase  = (lb >> 3) * QT;
    const int chBase = ch * CHUNK;
    const int nwv = wv * 64;

    if (tid < QT) thrF[tid] = inf_f();
    if (tid < 4 * QT) cnt[tid >> 5][tid & 31] = 0;
    __syncthreads();                                  // barrier #1 (init)

    const int am = L & 15, aq = L >> 4;
    half8 afh[2][4], afr[2][4];
    #pragma unroll
    for (int qt = 0; qt < 2; ++qt)
        #pragma unroll
        for (int ks = 0; ks < 4; ++ks) {
            size_t o = (size_t)(qbase + qt * 16 + am) * D_ + ks * 32 + aq * 8;
            afh[qt][ks] = *(const half8*)(Qh + o);
            afr[qt][ks] = *(const half8*)(Qr + o);
        }

    const half8* sp = (const half8*)Xs;
    volatile float* thv = thrF;

    #pragma unroll 1
    for (int it = 0; it < ITERS; ++it) {
        const int nbase = chBase + it * BN;
        const size_t segb = (size_t)((nbase + nwv) >> 4) * 4;
        floatx4 acc[2][4] = {};

        // ---- GEMM: B frags direct global->VGPR (L2-resident), ks-pipelined
        half8 bc[4], bn[4];
        #pragma unroll
        for (int nt = 0; nt < 4; ++nt)
            bc[nt] = sp[(segb + nt * 4 + 0) * 64 + L];
        #pragma unroll
        for (int ks = 0; ks < 4; ++ks) {
            if (ks < 3) {
                #pragma unroll
                for (int nt = 0; nt < 4; ++nt)
                    bn[nt] = sp[(segb + nt * 4 + ks + 1) * 64 + L];
            }
            #pragma unroll
            for (int nt = 0; nt < 4; ++nt)
                #pragma unroll
                for (int qt = 0; qt < 2; ++qt) {
                    acc[qt][nt] = __builtin_amdgcn_mfma_f32_16x16x32_f16(
                        afh[qt][ks], bc[nt], acc[qt][nt], 0, 0, 0);
                    acc[qt][nt] = __builtin_amdgcn_mfma_f32_16x16x32_f16(
                        afr[qt][ks], bc[nt], acc[qt][nt], 0, 0, 0);
                }
            if (ks < 3) {
                #pragma unroll
                for (int nt = 0; nt < 4; ++nt) bc[nt] = bn[nt];
            }
        }

        // ---- scores in place: s = tsq[n] - 2*dot   (C: row=q, col=n)
        float ts[4];
        #pragma unroll
        for (int nt = 0; nt < 4; ++nt)
            ts[nt] = tsq[nbase + nwv + nt * 16 + am];
        #pragma unroll
        for (int qt = 0; qt < 2; ++qt)
            #pragma unroll
            for (int nt = 0; nt < 4; ++nt)
                acc[qt][nt] = ts[nt] - 2.f * acc[qt][nt];

        // ---- threshold check, build need mask (bit = qt*16 + nt*4 + rg)
        float th[2][4];
        #pragma unroll
        for (int qt = 0; qt < 2; ++qt)
            #pragma unroll
            for (int rg = 0; rg < 4; ++rg)
                th[qt][rg] = thv[qt * 16 + aq * 4 + rg];
        unsigned int need = 0;
        #pragma unroll
        for (int qt = 0; qt < 2; ++qt)
            #pragma unroll
            for (int nt = 0; nt < 4; ++nt)
                #pragma unroll
                for (int rg = 0; rg < 4; ++rg)
                    if (acc[qt][nt][rg] < th[qt][rg])
                        need |= 1u << (qt * 16 + nt * 4 + rg);

        // ---- append / compact rounds (no barriers; wave-private buffers)
        #pragma unroll 1
        while (__any(need != 0)) {
            // append pass
            #pragma unroll
            for (int qt = 0; qt < 2; ++qt) {
                if (!__any(need & (0xffffu << (qt * 16)))) continue;
                #pragma unroll
                for (int nt = 0; nt < 4; ++nt) {
                    unsigned int g = 0xfu << (qt * 16 + nt * 4);
                    if (!__any(need & g)) continue;
                    #pragma unroll
                    for (int rg = 0; rg < 4; ++rg) {
                        unsigned int b = 1u << (qt * 16 + nt * 4 + rg);
                        if (need & b) {
                            int q = qt * 16 + aq * 4 + rg;
                            int pos = atomicAdd(&cnt[wv][q], 1);
                            if (pos < CW) {
                                cand[wv][q][pos] = pack_cand(
                                    acc[qt][nt][rg],
                                    (unsigned int)(nbase + nwv + nt * 16 + am));
                                need &= ~b;
                            }
                        }
                    }
                }
            }
            // trigger / fail detection
            int cL = (L < QT) ? *(volatile int*)&cnt[wv][L] : 0;
            ull ob = __ballot((L < QT) && (cL > CTRIG));
            unsigned int fq = 0;
            #pragma unroll
            for (int qt = 0; qt < 2; ++qt) {
                unsigned int m16 = (need >> (qt * 16)) & 0xffffu;
                unsigned int m4 = (m16 | (m16 >> 4) | (m16 >> 8) | (m16 >> 12)) & 0xfu;
                fq |= m4 << (qt * 16 + aq * 4);
            }
            #pragma unroll
            for (int d = 1; d < 64; d <<= 1) fq |= __shfl_xor(fq, d);
            unsigned int comp = (unsigned int)ob | fq;
            if (comp == 0) break;
            // compact flagged queries
            #pragma unroll 1
            while (comp) {
                int q = __ffs(comp) - 1; comp &= comp - 1;
                int c  = *(volatile int*)&cnt[wv][q];
                int cc = c < CW ? c : CW;
                ull v = (L < cc) ? cand[wv][q][L] : DEADC;
                float thq = thv[q];
                ull thKey = pack_cand(thq, 0u);
                bool alive = (L < cc) && (v < thKey);   // drop stale (>= thr)
                if (!alive) v = DEADC;
                ull balA = __ballot(alive);
                int live = __popcll(balA);
                if (live > KKEEP) {
                    v = bitonic64(v, L);
                    ull v31 = __shfl(v, KKEEP - 1);
                    if (L == 0) {
                        float t32 = unpack_score(v31);
                        thrF[q] = fminf(thq, t32);
                    }
                    if (L < KKEEP) cand[wv][q][L] = v;
                    if (L == 0) cnt[wv][q] = KKEEP;
                } else {
                    int pos = __popcll(balA & ((1ull << L) - 1ull));
                    if (alive) cand[wv][q][pos] = v;
                    if (L == 0) cnt[wv][q] = live;
                }
            }
            // re-filter remaining wants against refreshed thresholds
            #pragma unroll
            for (int qt = 0; qt < 2; ++qt)
                #pragma unroll
                for (int rg = 0; rg < 4; ++rg)
                    th[qt][rg] = thv[qt * 16 + aq * 4 + rg];
            unsigned int nn = 0;
            #pragma unroll
            for (int qt = 0; qt < 2; ++qt)
                #pragma unroll
                for (int nt = 0; nt < 4; ++nt)
                    #pragma unroll
                    for (int rg = 0; rg < 4; ++rg) {
                        unsigned int b = 1u << (qt * 16 + nt * 4 + rg);
                        if ((need & b) && acc[qt][nt][rg] < th[qt][rg])
                            nn |= b;
                    }
            need = nn;
        }
    }

    __syncthreads();                                  // barrier #2 (pre-merge)

    // ---- per-chunk merge: top-32 of the 4 wave buffers per query
    #pragma unroll 1
    for (int q8 = 0; q8 < 8; ++q8) {
        const int q = wv * 8 + q8;
        int c0 = min(*(volatile int*)&cnt[0][q], CW);
        int c1 = min(*(volatile int*)&cnt[1][q], CW);
        int c2 = min(*(volatile int*)&cnt[2][q], CW);
        int c3 = min(*(volatile int*)&cnt[3][q], CW);
        ull r0 = (L < c0) ? cand[0][q][L] : DEADC;
        ull r1 = (L < c1) ? cand[1][q][L] : DEADC;
        ull r2 = (L < c2) ? cand[2][q][L] : DEADC;
        ull r3 = (L < c3) ? cand[3][q][L] : DEADC;
        ull kept = DEADC;
        #pragma unroll 1
        for (int i = 0; i < K_; ++i) {
            ull g = u64min(u64min(r0, r1), u64min(r2, r3));
            g = u64min(g, __shfl_xor(g, 32)); g = u64min(g, __shfl_xor(g, 16));
            g = u64min(g, __shfl_xor(g, 8));  g = u64min(g, __shfl_xor(g, 4));
            g = u64min(g, __shfl_xor(g, 2));  g = u64min(g, __shfl_xor(g, 1));
            if (L == i) kept = g;
            bool has = (r0 == g) | (r1 == g) | (r2 == g) | (r3 == g);
            int fl = __ffsll((ull)__ballot(has)) - 1;
            if (L == fl) {
                if (r0 == g) r0 = DEADC; else if (r1 == g) r1 = DEADC;
                else if (r2 == g) r2 = DEADC; else r3 = DEADC;
            }
        }
        if (L < K_)
            candOut[((size_t)(qbase + q) * NCH + ch) * K_ + L] = kept;
    }
}

// ---------------------------------------------------- merge + exact rescore -
__global__ void merge_rescore(const ull* __restrict__ candIn,
                              const float* __restrict__ Qm,
                              const float* __restrict__ X,
                              const float* __restrict__ tsq,
                              const float* __restrict__ Ytr,
                              float* __restrict__ out)
{
    int L  = threadIdx.x & 63;
    int q  = blockIdx.x * 4 + (threadIdx.x >> 6);   // one wave per query
    const ull* p = candIn + (size_t)q * (NCH * K_); // 256 approx candidates
    ull r0 = p[L], r1 = p[L + 64], r2 = p[L + 128], r3 = p[L + 192];

    ull sel = DEADC;
    #pragma unroll 1
    for (int i = 0; i < MKEEP; ++i) {
        ull g = u64min(u64min(r0, r1), u64min(r2, r3));
        g = u64min(g, __shfl_xor(g, 32)); g = u64min(g, __shfl_xor(g, 16));
        g = u64min(g, __shfl_xor(g, 8));  g = u64min(g, __shfl_xor(g, 4));
        g = u64min(g, __shfl_xor(g, 2));  g = u64min(g, __shfl_xor(g, 1));
        if (L == i) sel = g;
        bool has = (r0 == g) | (r1 == g) | (r2 == g) | (r3 == g);
        int fl = __ffsll((ull)__ballot(has)) - 1;
        if (L == fl) {
            if (r0 == g) r0 = DEADC; else if (r1 == g) r1 = DEADC;
            else if (r2 == g) r2 = DEADC; else r3 = DEADC;
        }
    }

    // exact fp32 rescore (wave-cooperative dot per candidate)
    float2 qv = *(const float2*)(Qm + (size_t)q * D_ + 2 * L);
    ull key = DEADC;
    #pragma unroll 1
    for (int c = 0; c < MKEEP; ++c) {
        ull s = __shfl(sel, c);
        unsigned int n = (unsigned int)(s & 0xffffffffu);
        float2 xv = *(const float2*)(X + (size_t)n * D_ + 2 * L);
        float pd = qv.x * xv.x + qv.y * xv.y;
        pd += __shfl_xor(pd, 32); pd += __shfl_xor(pd, 16);
        pd += __shfl_xor(pd, 8);  pd += __shfl_xor(pd, 4);
        pd += __shfl_xor(pd, 2);  pd += __shfl_xor(pd, 1);
        float scv = tsq[n] - 2.f * pd;
        if (L == c) key = pack_cand(scv, n);
    }

    // exact top-32 of MKEEP, mean of y
    ull kv = key;
    bool kept = false;
    #pragma unroll 1
    for (int i = 0; i < K_; ++i) {
        ull g = kv;
        g = u64min(g, __shfl_xor(g, 32)); g = u64min(g, __shfl_xor(g, 16));
        g = u64min(g, __shfl_xor(g, 8));  g = u64min(g, __shfl_xor(g, 4));
        g = u64min(g, __shfl_xor(g, 2));  g = u64min(g, __shfl_xor(g, 1));
        int fl = __ffsll((ull)__ballot(kv == g)) - 1;
        if (L == fl) { kv = DEADC; kept = true; }
    }
    float ys = kept ? Ytr[(unsigned int)(key & 0xffffffffu)] : 0.f;
    ys += __shfl_xor(ys, 32); ys += __shfl_xor(ys, 16); ys += __shfl_xor(ys, 8);
    ys += __shfl_xor(ys, 4);  ys += __shfl_xor(ys, 2);  ys += __shfl_xor(ys, 1);
    if (L == 0) out[q] = ys * (1.f / K_);
}

// ------------------------------------------------------------- launch -------
extern "C" void kernel_launch(void* const* d_in, const int* in_sizes, int n_in,
                              void* d_out, int out_size, void* d_ws, size_t ws_size,
                              hipStream_t stream)
{
    const float* Qm  = (const float*)d_in[0];   // [4096,128]
    const float* X   = (const float*)d_in[1];   // [100000,128]
    const float* Ytr = (const float*)d_in[2];   // [100000]
    float* out = (float*)d_out;                 // [4096]

    char* w = (char*)d_ws;
    __half* Xs = (__half*)w;                         w += (size_t)NPAD * D_ * 2;  // 25.7 MB
    __half* Qh = (__half*)w;                         w += (size_t)Q_ * D_ * 2;    // 1 MB
    __half* Qr = (__half*)w;                         w += (size_t)Q_ * D_ * 2;    // 1 MB
    float*  ts = (float*)w;                          w += (size_t)NPAD * 4;       // 0.4 MB
    ull*    cd = (ull*)w;                            // 8.4 MB  (total ~36.5 MB)

    prep_xs<<<NPAD / 64, 256, 0, stream>>>(X, Xs, ts);
    prep_q<<<Q_ / 4, 256, 0, stream>>>(Qm, Qh, Qr);
    knn_main<<<(Q_ / QT) * NCH, 256, 0, stream>>>(Qh, Qr, Xs, ts, cd);
    merge_rescore<<<Q_ / 4, 256, 0, stream>>>(cd, Qm, X, ts, Ytr, out);
}

// Round 6
// 816.676 us; speedup vs baseline: 1.7599x; 1.7599x over previous
//
#include <hip/hip_runtime.h>
#include <hip/hip_fp16.h>
#include <cstdint>
#include <cstddef>

// KNN regressor v6 — fixed precomputed thresholds, stateless K-loop.
//   score[n] = tsq[n] - 2*dot(q, x_n)
// approx dot via fp16 split (qh+qr)·xh; error |approx-exact| = |2 q·xr + rnd|
//   <= E_q = 2|q|·maxXr + 0.02  (device-computed, rigorous).
// Pipeline: memset -> prep_xs -> prep_q -> prep_sam -> sample_T -> knn_main
//           -> finalize -> fallback.
// sample_T: T_q = 16th smallest of per-lane-top2 approx scores over an 8192
//   sample (rank>=16 guaranteed -> E[#cand]~220, P[<32]~1e-9).
// knn_main: append (approx,n) to global per-query list iff approx < T_q+E_q.
// finalize: sort by approx, exact-rescore top-64, verify (c>=32; window
//   A63-E>exact32; exact32<T_q); any failure -> flag -> fallback brute force.
//
// MFMA 16x16x32 f16 layouts (HW-verified, learn_hip m89/m91/m120):
//   A[m][k]: m=lane&15, k=(lane>>4)*8+j ; B[k][n]: n=lane&15, k=(lane>>4)*8+j
//   C[m][n]: n=lane&15, m=(lane>>4)*4+reg
// Xs swizzle: seg s=(n>>4)*4+ks holds at half8-idx s*64+L the halves of
//   row (n&~15)+(L&15), k = ks*32+(L>>4)*8..+8  (1 KB per segment).

constexpr int Q_  = 4096;
constexpr int N_  = 100000;
constexpr int D_  = 128;
constexpr int K_  = 32;

constexpr int QT    = 32;
constexpr int BN    = 256;
constexpr int NCH   = 8;
constexpr int CHUNK = 12544;          // 49*256
constexpr int ITERS = CHUNK / BN;     // 49
constexpr int NPAD  = NCH * CHUNK;    // 100352
constexpr int CAP   = 512;            // per-query global candidate capacity
constexpr int NG    = CAP / 64;       // 8 groups
constexpr int SAMP_M      = 8192;
constexpr int SAMP_STRIDE = 12;
constexpr int SAMP_OFF    = 5;        // max n = 8191*12+5 = 98297 < N_
constexpr int SAMP_ITERS  = SAMP_M / BN;   // 32

typedef __attribute__((ext_vector_type(8))) _Float16 half8;
typedef __attribute__((ext_vector_type(4))) float    floatx4;
typedef unsigned long long ull;

#define DEV __device__ __forceinline__
constexpr ull DEADC = ~0ull;

DEV ull pack_cand(float score, unsigned int n) {
    unsigned int s = __float_as_uint(score);
    s = (s & 0x80000000u) ? ~s : (s | 0x80000000u);   // monotone u32 key
    return ((ull)s << 32) | (ull)n;
}
DEV float unpack_score(ull k) {
    unsigned int s = (unsigned int)(k >> 32);
    s = (s & 0x80000000u) ? (s ^ 0x80000000u) : ~s;
    return __uint_as_float(s);
}
DEV ull u64min(ull a, ull b) { return a < b ? a : b; }
DEV float inf_f() { return __int_as_float(0x7f800000); }

DEV ull bitonic64(ull v, int L) {            // full sort, ascending
    #pragma unroll
    for (int k2 = 2; k2 <= 64; k2 <<= 1)
        #pragma unroll
        for (int j2 = k2 >> 1; j2 >= 1; j2 >>= 1) {
            ull o = __shfl_xor(v, j2);
            bool up = ((L & k2) == 0);
            bool lo = ((L & j2) == 0);
            ull mn = u64min(v, o), mx = v ^ o ^ mn;
            v = (lo == up) ? mn : mx;
        }
    return v;
}
DEV ull bimerge64(ull v, int L) {            // sort a bitonic seq, ascending
    #pragma unroll
    for (int j2 = 32; j2 >= 1; j2 >>= 1) {
        ull o = __shfl_xor(v, j2);
        ull mn = u64min(v, o), mx = v ^ o ^ mn;
        v = ((L & j2) == 0) ? mn : mx;
    }
    return v;
}

// ---------------------------------------------------------------- prep ------
__global__ void prep_xs(const float* __restrict__ X, __half* __restrict__ Xs,
                        float* __restrict__ tsq, unsigned* __restrict__ maxXr2) {
    int tid = threadIdx.x;
    int L = tid & 63, wv = tid >> 6;
    int t16 = blockIdx.x * 4 + wv;            // < NPAD/16
    int am = L & 15, aq = L >> 4;
    int r = t16 * 16 + am;
    float ssq = 0.f, xr2 = 0.f;
    #pragma unroll
    for (int ks = 0; ks < 4; ++ks) {
        int c = ks * 32 + aq * 8;
        float v0=0,v1=0,v2=0,v3=0,v4=0,v5=0,v6=0,v7=0;
        if (r < N_) {
            float4 a = *(const float4*)(X + (size_t)r * D_ + c);
            float4 b = *(const float4*)(X + (size_t)r * D_ + c + 4);
            v0=a.x; v1=a.y; v2=a.z; v3=a.w; v4=b.x; v5=b.y; v6=b.z; v7=b.w;
        }
        half8 h;
        h[0]=(_Float16)v0; h[1]=(_Float16)v1; h[2]=(_Float16)v2; h[3]=(_Float16)v3;
        h[4]=(_Float16)v4; h[5]=(_Float16)v5; h[6]=(_Float16)v6; h[7]=(_Float16)v7;
        float r0=v0-(float)h[0], r1=v1-(float)h[1], r2=v2-(float)h[2], r3=v3-(float)h[3];
        float r4=v4-(float)h[4], r5=v5-(float)h[5], r6=v6-(float)h[6], r7=v7-(float)h[7];
        ssq += v0*v0+v1*v1+v2*v2+v3*v3+v4*v4+v5*v5+v6*v6+v7*v7;
        xr2 += r0*r0+r1*r1+r2*r2+r3*r3+r4*r4+r5*r5+r6*r6+r7*r7;
        *(half8*)(Xs + ((size_t)(t16 * 4 + ks)) * 512 + L * 8) = h;
    }
    ssq += __shfl_xor(ssq, 16); ssq += __shfl_xor(ssq, 32);   // rowwise
    xr2 += __shfl_xor(xr2, 16); xr2 += __shfl_xor(xr2, 32);
    if (aq == 0) tsq[r] = (r < N_) ? ssq : inf_f();
    float m = xr2;                                            // max over 16 rows
    m = fmaxf(m, __shfl_xor(m, 1)); m = fmaxf(m, __shfl_xor(m, 2));
    m = fmaxf(m, __shfl_xor(m, 4)); m = fmaxf(m, __shfl_xor(m, 8));
    if (L == 0) atomicMax(maxXr2, __float_as_uint(m));        // pos floats monotone
}

__global__ void prep_q(const float* __restrict__ Qm, __half* __restrict__ Qh,
                       __half* __restrict__ Qr, float* __restrict__ qsq) {
    int L = threadIdx.x & 63;
    int r = blockIdx.x * 4 + (threadIdx.x >> 6);
    float2 x = *(const float2*)(Qm + (size_t)r * D_ + 2 * L);
    __half h0 = __float2half(x.x), h1 = __float2half(x.y);
    size_t o = (size_t)r * D_ + 2 * L;
    Qh[o] = h0; Qh[o + 1] = h1;
    Qr[o]     = __float2half(x.x - __half2float(h0));
    Qr[o + 1] = __float2half(x.y - __half2float(h1));
    float s = x.x * x.x + x.y * x.y;
    s += __shfl_xor(s, 32); s += __shfl_xor(s, 16); s += __shfl_xor(s, 8);
    s += __shfl_xor(s, 4);  s += __shfl_xor(s, 2);  s += __shfl_xor(s, 1);
    if (L == 0) qsq[r] = s;
}

__global__ void prep_sam(const float* __restrict__ X, __half* __restrict__ Xsam,
                         float* __restrict__ tsqS) {
    int tid = threadIdx.x;
    int L = tid & 63, wv = tid >> 6;
    int t16 = blockIdx.x * 4 + wv;            // < 512
    int am = L & 15, aq = L >> 4;
    int j = t16 * 16 + am;
    int n = j * SAMP_STRIDE + SAMP_OFF;       // always < N_
    float ssq = 0.f;
    #pragma unroll
    for (int ks = 0; ks < 4; ++ks) {
        int c = ks * 32 + aq * 8;
        float4 a = *(const float4*)(X + (size_t)n * D_ + c);
        float4 b = *(const float4*)(X + (size_t)n * D_ + c + 4);
        half8 h;
        h[0]=(_Float16)a.x; h[1]=(_Float16)a.y; h[2]=(_Float16)a.z; h[3]=(_Float16)a.w;
        h[4]=(_Float16)b.x; h[5]=(_Float16)b.y; h[6]=(_Float16)b.z; h[7]=(_Float16)b.w;
        ssq += a.x*a.x + a.y*a.y + a.z*a.z + a.w*a.w
             + b.x*b.x + b.y*b.y + b.z*b.z + b.w*b.w;
        *(half8*)(Xsam + ((size_t)(t16 * 4 + ks)) * 512 + L * 8) = h;
    }
    ssq += __shfl_xor(ssq, 16); ssq += __shfl_xor(ssq, 32);
    if (aq == 0) tsqS[j] = ssq;
}

// ---------------------------------------------------------- sample_T --------
__global__ __launch_bounds__(256, 2) void sample_T(
    const __half* __restrict__ Qh, const __half* __restrict__ Qr,
    const __half* __restrict__ Xsam, const float* __restrict__ tsqS,
    const float* __restrict__ qsq, const unsigned* __restrict__ maxXr2,
    float* __restrict__ Teff, float* __restrict__ rawT, float* __restrict__ EwA)
{
    __shared__ float sT[QT][130];
    const int tid = threadIdx.x, L = tid & 63, wv = tid >> 6;
    const int qbase = blockIdx.x * QT;
    const int nwv = wv * 64;
    const int am = L & 15, aq = L >> 4;

    half8 afh[2][4], afr[2][4];
    #pragma unroll
    for (int qt = 0; qt < 2; ++qt)
        #pragma unroll
        for (int ks = 0; ks < 4; ++ks) {
            size_t o = (size_t)(qbase + qt * 16 + am) * D_ + ks * 32 + aq * 8;
            afh[qt][ks] = *(const half8*)(Qh + o);
            afr[qt][ks] = *(const half8*)(Qr + o);
        }
    const half8* sp = (const half8*)Xsam;

    float t2a[2][4], t2b[2][4];
    #pragma unroll
    for (int qt = 0; qt < 2; ++qt)
        #pragma unroll
        for (int rg = 0; rg < 4; ++rg) { t2a[qt][rg] = inf_f(); t2b[qt][rg] = inf_f(); }

    #pragma unroll 1
    for (int it = 0; it < SAMP_ITERS; ++it) {
        const int nbase = it * BN;
        const size_t segb = (size_t)((nbase + nwv) >> 4) * 4;
        floatx4 acc[2][4] = {};
        #pragma unroll
        for (int ks = 0; ks < 4; ++ks) {
            half8 bf[4];
            #pragma unroll
            for (int nt = 0; nt < 4; ++nt)
                bf[nt] = sp[(segb + nt * 4 + ks) * 64 + L];
            #pragma unroll
            for (int nt = 0; nt < 4; ++nt)
                #pragma unroll
                for (int qt = 0; qt < 2; ++qt) {
                    acc[qt][nt] = __builtin_amdgcn_mfma_f32_16x16x32_f16(
                        afh[qt][ks], bf[nt], acc[qt][nt], 0, 0, 0);
                    acc[qt][nt] = __builtin_amdgcn_mfma_f32_16x16x32_f16(
                        afr[qt][ks], bf[nt], acc[qt][nt], 0, 0, 0);
                }
        }
        float ts[4];
        #pragma unroll
        for (int nt = 0; nt < 4; ++nt)
            ts[nt] = tsqS[nbase + nwv + nt * 16 + am];
        #pragma unroll
        for (int qt = 0; qt < 2; ++qt)
            #pragma unroll
            for (int rg = 0; rg < 4; ++rg) {
                float m1 = t2a[qt][rg], m2 = t2b[qt][rg];
                #pragma unroll
                for (int nt = 0; nt < 4; ++nt) {
                    float v = ts[nt] - 2.f * acc[qt][nt][rg];
                    if (v < m2) { if (v < m1) { m2 = m1; m1 = v; } else m2 = v; }
                }
                t2a[qt][rg] = m1; t2b[qt][rg] = m2;
            }
    }
    #pragma unroll
    for (int qt = 0; qt < 2; ++qt)
        #pragma unroll
        for (int rg = 0; rg < 4; ++rg) {
            int q = qt * 16 + aq * 4 + rg;
            sT[q][wv * 32 + am * 2 + 0] = t2a[qt][rg];
            sT[q][wv * 32 + am * 2 + 1] = t2b[qt][rg];
        }
    __syncthreads();

    const float E = 2.f * sqrtf(qsq[qbase + 0]) * 0.f;  // placeholder (per-q below)
    (void)E;
    #pragma unroll 1
    for (int j = 0; j < 8; ++j) {
        int q = wv * 8 + j;
        float a = sT[q][2 * L], b = sT[q][2 * L + 1];
        float g = 0.f;
        #pragma unroll 1
        for (int r = 0; r < 16; ++r) {
            float mn = fminf(a, b);
            mn = fminf(mn, __shfl_xor(mn, 32)); mn = fminf(mn, __shfl_xor(mn, 16));
            mn = fminf(mn, __shfl_xor(mn, 8));  mn = fminf(mn, __shfl_xor(mn, 4));
            mn = fminf(mn, __shfl_xor(mn, 2));  mn = fminf(mn, __shfl_xor(mn, 1));
            g = mn;
            ull ba = __ballot(a == g);
            if (ba) { if (L == __ffsll(ba) - 1) a = inf_f(); }
            else    { ull bb = __ballot(b == g); if (L == __ffsll(bb) - 1) b = inf_f(); }
        }
        if (L == 0) {
            int gq = qbase + q;
            float e = 2.f * sqrtf(qsq[gq]) * sqrtf(__uint_as_float(*maxXr2)) + 0.02f;
            rawT[gq] = g; EwA[gq] = e; Teff[gq] = g + e;
        }
    }
}

// ------------------------------------------------------------- main ---------
__global__ __launch_bounds__(256, 3) void knn_main(
    const __half* __restrict__ Qh, const __half* __restrict__ Qr,
    const __half* __restrict__ Xs, const float* __restrict__ tsq,
    const float* __restrict__ Teff, ull* __restrict__ candG,
    int* __restrict__ cntG, int* __restrict__ flagF)
{
    const int tid = threadIdx.x, L = tid & 63, wv = tid >> 6;
    const int lb = blockIdx.x, ch = lb & 7;                 // XCD-affine chunk
    const int qbase = (lb >> 3) * QT, chBase = ch * CHUNK, nwv = wv * 64;
    const int am = L & 15, aq = L >> 4;

    float th[2][4];
    #pragma unroll
    for (int qt = 0; qt < 2; ++qt)
        #pragma unroll
        for (int rg = 0; rg < 4; ++rg)
            th[qt][rg] = Teff[qbase + qt * 16 + aq * 4 + rg];

    half8 afh[2][4], afr[2][4];
    #pragma unroll
    for (int qt = 0; qt < 2; ++qt)
        #pragma unroll
        for (int ks = 0; ks < 4; ++ks) {
            size_t o = (size_t)(qbase + qt * 16 + am) * D_ + ks * 32 + aq * 8;
            afh[qt][ks] = *(const half8*)(Qh + o);
            afr[qt][ks] = *(const half8*)(Qr + o);
        }
    const half8* sp = (const half8*)Xs;

    #pragma unroll 1
    for (int it = 0; it < ITERS; ++it) {
        const int nbase = chBase + it * BN;
        const size_t segb = (size_t)((nbase + nwv) >> 4) * 4;
        floatx4 acc[2][4] = {};
        #pragma unroll
        for (int ks = 0; ks < 4; ++ks) {
            half8 bf[4];
            #pragma unroll
            for (int nt = 0; nt < 4; ++nt)
                bf[nt] = sp[(segb + nt * 4 + ks) * 64 + L];
            #pragma unroll
            for (int nt = 0; nt < 4; ++nt)
                #pragma unroll
                for (int qt = 0; qt < 2; ++qt) {
                    acc[qt][nt] = __builtin_amdgcn_mfma_f32_16x16x32_f16(
                        afh[qt][ks], bf[nt], acc[qt][nt], 0, 0, 0);
                    acc[qt][nt] = __builtin_amdgcn_mfma_f32_16x16x32_f16(
                        afr[qt][ks], bf[nt], acc[qt][nt], 0, 0, 0);
                }
        }
        float ts[4];
        #pragma unroll
        for (int nt = 0; nt < 4; ++nt)
            ts[nt] = tsq[nbase + nwv + nt * 16 + am];
        #pragma unroll
        for (int qt = 0; qt < 2; ++qt)
            #pragma unroll
            for (int nt = 0; nt < 4; ++nt)
                acc[qt][nt] = ts[nt] - 2.f * acc[qt][nt];

        unsigned need = 0;
        #pragma unroll
        for (int qt = 0; qt < 2; ++qt)
            #pragma unroll
            for (int nt = 0; nt < 4; ++nt)
                #pragma unroll
                for (int rg = 0; rg < 4; ++rg)
                    if (acc[qt][nt][rg] < th[qt][rg])
                        need |= 1u << (qt * 16 + nt * 4 + rg);

        if (__any(need != 0)) {
            #pragma unroll
            for (int qt = 0; qt < 2; ++qt) {
                #pragma unroll
                for (int nt = 0; nt < 4; ++nt) {
                    unsigned grp = 0xfu << (qt * 16 + nt * 4);
                    if (__any((need & grp) != 0)) {
                        #pragma unroll
                        for (int rg = 0; rg < 4; ++rg) {
                            unsigned b = 1u << (qt * 16 + nt * 4 + rg);
                            if (need & b) {
                                int gq = qbase + qt * 16 + aq * 4 + rg;
                                unsigned n = (unsigned)(nbase + nwv + nt * 16 + am);
                                int pos = atomicAdd(&cntG[gq], 1);
                                if (pos < CAP)
                                    candG[(size_t)gq * CAP + pos] =
                                        pack_cand(acc[qt][nt][rg], n);
                                else
                                    flagF[gq] = 1;
                            }
                        }
                    }
                }
            }
        }
    }
}

// ------------------------------------------------------------ finalize ------
__global__ void finalize(const ull* __restrict__ candG, const int* __restrict__ cntG,
                         int* __restrict__ flagF, const float* __restrict__ Qm,
                         const float* __restrict__ X, const float* __restrict__ tsq,
                         const float* __restrict__ rawT, const float* __restrict__ EwA,
                         const float* __restrict__ Ytr, float* __restrict__ out)
{
    int L = threadIdx.x & 63;
    int q = blockIdx.x * 4 + (threadIdx.x >> 6);
    if (flagF[q]) return;                       // fallback handles
    int c = cntG[q];
    if (c < K_) { if (L == 0) flagF[q] = 1; return; }

    const ull* base = candG + (size_t)q * CAP;
    ull s = (L < c) ? base[L] : DEADC;
    s = bitonic64(s, L);
    for (int g = 1; g < NG && g * 64 < c; ++g) {
        ull v = (g * 64 + L < c) ? base[g * 64 + L] : DEADC;
        v = bitonic64(v, L);
        ull w = __shfl(v, 63 - L);              // reversed
        s = bimerge64(u64min(s, w), L);         // keep 64 smallest, sorted
    }

    int cr = c < 64 ? c : 64;
    unsigned n = (unsigned)(s & 0xffffffffu);
    ull pe = DEADC;
    if (L < cr) {
        const float4* xp = (const float4*)(X + (size_t)n * D_);
        const float4* qp = (const float4*)(Qm + (size_t)q * D_);
        float d = 0.f;
        #pragma unroll 8
        for (int i = 0; i < 32; ++i) {
            float4 xv = xp[i], qv = qp[i];
            d += qv.x * xv.x + qv.y * xv.y + qv.z * xv.z + qv.w * xv.w;
        }
        pe = pack_cand(tsq[n] - 2.f * d, n);
    }
    ull pe2 = bitonic64(pe, L);
    float exact31 = unpack_score(__shfl(pe2, K_ - 1));
    bool ok = exact31 < rawT[q];
    if (c > 64) {
        float A63 = unpack_score(__shfl(s, 63));
        ok = ok && (A63 - EwA[q] > exact31);
    }
    if (!ok) { if (L == 0) flagF[q] = 1; return; }
    float ys = 0.f;
    if (L < K_) ys = Ytr[(unsigned)(pe2 & 0xffffffffu)];
    ys += __shfl_xor(ys, 32); ys += __shfl_xor(ys, 16); ys += __shfl_xor(ys, 8);
    ys += __shfl_xor(ys, 4);  ys += __shfl_xor(ys, 2);  ys += __shfl_xor(ys, 1);
    if (L == 0) out[q] = ys * (1.f / K_);
}

// ------------------------------------------------------------ fallback ------
__global__ void fallback(const int* __restrict__ flagF, const float* __restrict__ Qm,
                         const float* __restrict__ X, const float* __restrict__ tsq,
                         const float* __restrict__ Ytr, float* __restrict__ out)
{
    int L = threadIdx.x & 63;
    int q = blockIdx.x * 4 + (threadIdx.x >> 6);
    if (!flagF[q]) return;                      // ~never taken
    const float4* qp = (const float4*)(Qm + (size_t)q * D_);
    ull last = 0;
    float ysum = 0.f;
    for (int r = 0; r < K_; ++r) {
        ull best = DEADC;
        for (int j = 0; j < NPAD / 64; ++j) {
            int n = j * 64 + L;
            if (n < N_) {
                const float4* xp = (const float4*)(X + (size_t)n * D_);
                float d = 0.f;
                #pragma unroll 4
                for (int i = 0; i < 32; ++i) {
                    float4 xv = xp[i], qv = qp[i];
                    d += qv.x * xv.x + qv.y * xv.y + qv.z * xv.z + qv.w * xv.w;
                }
                ull k = pack_cand(tsq[n] - 2.f * d, n);
                if (k > last && k < best) best = k;
            }
        }
        best = u64min(best, __shfl_xor(best, 32));
        best = u64min(best, __shfl_xor(best, 16));
        best = u64min(best, __shfl_xor(best, 8));
        best = u64min(best, __shfl_xor(best, 4));
        best = u64min(best, __shfl_xor(best, 2));
        best = u64min(best, __shfl_xor(best, 1));
        if (L == 0) ysum += Ytr[(unsigned)(best & 0xffffffffu)];
        last = best;
    }
    if (L == 0) out[q] = ysum * (1.f / K_);
}

// ------------------------------------------------------------- launch -------
extern "C" void kernel_launch(void* const* d_in, const int* in_sizes, int n_in,
                              void* d_out, int out_size, void* d_ws, size_t ws_size,
                              hipStream_t stream)
{
    const float* Qm  = (const float*)d_in[0];   // [4096,128]
    const float* X   = (const float*)d_in[1];   // [100000,128]
    const float* Ytr = (const float*)d_in[2];   // [100000]
    float* out = (float*)d_out;                 // [4096]

    char* w = (char*)d_ws;
    auto alloc = [&](size_t bytes) {
        char* p = w; w += (bytes + 255) & ~(size_t)255; return p;
    };
    __half* Xs   = (__half*)  alloc((size_t)NPAD * D_ * 2);   // 25.7 MB
    __half* Qh   = (__half*)  alloc((size_t)Q_ * D_ * 2);     // 1 MB
    __half* Qr   = (__half*)  alloc((size_t)Q_ * D_ * 2);     // 1 MB
    float*  ts   = (float*)   alloc((size_t)NPAD * 4);        // 0.4 MB
    __half* Xsm  = (__half*)  alloc((size_t)SAMP_M * D_ * 2); // 2 MB
    float*  tsS  = (float*)   alloc((size_t)SAMP_M * 4);      // 32 KB
    ull*    cd   = (ull*)     alloc((size_t)Q_ * CAP * 8);    // 16.8 MB
    int*    cnt  = (int*)     alloc((size_t)Q_ * 4);          // 16 KB
    int*    flg  = (int*)     alloc((size_t)Q_ * 4);          // 16 KB
    unsigned* mxr= (unsigned*)alloc(256);
    float*  Tef  = (float*)   alloc((size_t)Q_ * 4);
    float*  rwT  = (float*)   alloc((size_t)Q_ * 4);
    float*  Ew   = (float*)   alloc((size_t)Q_ * 4);
    float*  qs   = (float*)   alloc((size_t)Q_ * 4);          // total ~47.3 MB

    // zero cnt + flags + maxXr2 (contiguous, 256-aligned allocs)
    hipMemsetAsync(cnt, 0, (size_t)Q_ * 4 + (size_t)Q_ * 4 + 256, stream);

    prep_xs <<<NPAD / 64, 256, 0, stream>>>(X, Xs, ts, mxr);
    prep_q  <<<Q_ / 4,   256, 0, stream>>>(Qm, Qh, Qr, qs);
    prep_sam<<<SAMP_M / 64, 256, 0, stream>>>(X, Xsm, tsS);
    sample_T<<<Q_ / QT,  256, 0, stream>>>(Qh, Qr, Xsm, tsS, qs, mxr, Tef, rwT, Ew);
    knn_main<<<(Q_ / QT) * NCH, 256, 0, stream>>>(Qh, Qr, Xs, ts, Tef, cd, cnt, flg);
    finalize<<<Q_ / 4,   256, 0, stream>>>(cd, cnt, flg, Qm, X, ts, rwT, Ew, Ytr, out);
    fallback<<<Q_ / 4,   256, 0, stream>>>(flg, Qm, X, ts, Ytr, out);
}

// Round 7
// 809.547 us; speedup vs baseline: 1.7754x; 1.0088x over previous
//
#include <hip/hip_runtime.h>
#include <hip/hip_fp16.h>
#include <cstdint>
#include <cstddef>

// KNN regressor v7 — fixed thresholds + LDS candidate buffers + 2x grid.
//   score[n] = tsq[n] - 2*dot(q, x_n)
// approx dot via fp16 split (qh+qr)·xh; |approx-exact| <= E_q = 2|q|·maxXr+0.02.
// Pipeline: memset -> prep_xs -> prep_q -> prep_sam -> sample_T -> knn_main
//           -> finalize -> fallback.
// knn_main: per-(query,chunk) LDS lists (LDS atomics only), dumped to fixed
//   global slots (no global atomics). Grid 2048 blocks (NCH=16 chunks).
// finalize: bitonic-merge 16 sorted lists -> top-64 approx -> exact rescore
//   -> verify (ctot>=32; exact31<rawT; A63-E>exact31 if truncated) -> mean(y);
//   any failure -> flag -> fallback brute force (exactness guaranteed).
//
// MFMA 16x16x32 f16 layouts (HW-verified, learn_hip m89/m91/m120):
//   A[m][k]: m=lane&15, k=(lane>>4)*8+j ; B[k][n]: n=lane&15, k=(lane>>4)*8+j
//   C[m][n]: n=lane&15, m=(lane>>4)*4+reg
// Xs swizzle: seg s=(n>>4)*4+ks holds at half8-idx s*64+L the halves of
//   row (n&~15)+(L&15), k = ks*32+(L>>4)*8..+8  (1 KB per segment).

constexpr int Q_  = 4096;
constexpr int N_  = 100000;
constexpr int D_  = 128;
constexpr int K_  = 32;

constexpr int QT    = 32;
constexpr int BN    = 256;
constexpr int NCH   = 16;             // chunks (ch = lb & 15; XCD = lb & 7)
constexpr int CHUNK = 6400;           // 25*256
constexpr int ITERS = CHUNK / BN;     // 25
constexpr int NPAD  = NCH * CHUNK;    // 102400
constexpr int CW    = 48;             // per-(query,chunk) candidate capacity
constexpr int QTS   = 16;             // sample_T queries per block
constexpr int SAMP_M      = 8192;
constexpr int SAMP_STRIDE = 12;
constexpr int SAMP_OFF    = 5;        // max n = 8191*12+5 = 98297 < N_
constexpr int SAMP_ITERS  = SAMP_M / BN;   // 32

typedef __attribute__((ext_vector_type(8))) _Float16 half8;
typedef __attribute__((ext_vector_type(4))) float    floatx4;
typedef unsigned long long ull;

#define DEV __device__ __forceinline__
constexpr ull DEADC = ~0ull;

DEV ull pack_cand(float score, unsigned int n) {
    unsigned int s = __float_as_uint(score);
    s = (s & 0x80000000u) ? ~s : (s | 0x80000000u);   // monotone u32 key
    return ((ull)s << 32) | (ull)n;
}
DEV float unpack_score(ull k) {
    unsigned int s = (unsigned int)(k >> 32);
    s = (s & 0x80000000u) ? (s ^ 0x80000000u) : ~s;
    return __uint_as_float(s);
}
DEV ull u64min(ull a, ull b) { return a < b ? a : b; }
DEV float inf_f() { return __int_as_float(0x7f800000); }

DEV ull bitonic64(ull v, int L) {            // full sort, ascending
    #pragma unroll
    for (int k2 = 2; k2 <= 64; k2 <<= 1)
        #pragma unroll
        for (int j2 = k2 >> 1; j2 >= 1; j2 >>= 1) {
            ull o = __shfl_xor(v, j2);
            bool up = ((L & k2) == 0);
            bool lo = ((L & j2) == 0);
            ull mn = u64min(v, o), mx = v ^ o ^ mn;
            v = (lo == up) ? mn : mx;
        }
    return v;
}
DEV ull bimerge64(ull v, int L) {            // sort a bitonic seq, ascending
    #pragma unroll
    for (int j2 = 32; j2 >= 1; j2 >>= 1) {
        ull o = __shfl_xor(v, j2);
        ull mn = u64min(v, o), mx = v ^ o ^ mn;
        v = ((L & j2) == 0) ? mn : mx;
    }
    return v;
}

// ---------------------------------------------------------------- prep ------
__global__ void prep_xs(const float* __restrict__ X, __half* __restrict__ Xs,
                        float* __restrict__ tsq, unsigned* __restrict__ maxXr2) {
    int tid = threadIdx.x;
    int L = tid & 63, wv = tid >> 6;
    int t16 = blockIdx.x * 4 + wv;            // < NPAD/16
    int am = L & 15, aq = L >> 4;
    int r = t16 * 16 + am;
    float ssq = 0.f, xr2 = 0.f;
    #pragma unroll
    for (int ks = 0; ks < 4; ++ks) {
        int c = ks * 32 + aq * 8;
        float v0=0,v1=0,v2=0,v3=0,v4=0,v5=0,v6=0,v7=0;
        if (r < N_) {
            float4 a = *(const float4*)(X + (size_t)r * D_ + c);
            float4 b = *(const float4*)(X + (size_t)r * D_ + c + 4);
            v0=a.x; v1=a.y; v2=a.z; v3=a.w; v4=b.x; v5=b.y; v6=b.z; v7=b.w;
        }
        half8 h;
        h[0]=(_Float16)v0; h[1]=(_Float16)v1; h[2]=(_Float16)v2; h[3]=(_Float16)v3;
        h[4]=(_Float16)v4; h[5]=(_Float16)v5; h[6]=(_Float16)v6; h[7]=(_Float16)v7;
        float r0=v0-(float)h[0], r1=v1-(float)h[1], r2=v2-(float)h[2], r3=v3-(float)h[3];
        float r4=v4-(float)h[4], r5=v5-(float)h[5], r6=v6-(float)h[6], r7=v7-(float)h[7];
        ssq += v0*v0+v1*v1+v2*v2+v3*v3+v4*v4+v5*v5+v6*v6+v7*v7;
        xr2 += r0*r0+r1*r1+r2*r2+r3*r3+r4*r4+r5*r5+r6*r6+r7*r7;
        *(half8*)(Xs + ((size_t)(t16 * 4 + ks)) * 512 + L * 8) = h;
    }
    ssq += __shfl_xor(ssq, 16); ssq += __shfl_xor(ssq, 32);   // rowwise
    xr2 += __shfl_xor(xr2, 16); xr2 += __shfl_xor(xr2, 32);
    if (aq == 0) tsq[r] = (r < N_) ? ssq : inf_f();
    float m = xr2;                                            // max over 16 rows
    m = fmaxf(m, __shfl_xor(m, 1)); m = fmaxf(m, __shfl_xor(m, 2));
    m = fmaxf(m, __shfl_xor(m, 4)); m = fmaxf(m, __shfl_xor(m, 8));
    if (L == 0) atomicMax(maxXr2, __float_as_uint(m));        // pos floats monotone
}

__global__ void prep_q(const float* __restrict__ Qm, __half* __restrict__ Qh,
                       __half* __restrict__ Qr, float* __restrict__ qsq) {
    int L = threadIdx.x & 63;
    int r = blockIdx.x * 4 + (threadIdx.x >> 6);
    float2 x = *(const float2*)(Qm + (size_t)r * D_ + 2 * L);
    __half h0 = __float2half(x.x), h1 = __float2half(x.y);
    size_t o = (size_t)r * D_ + 2 * L;
    Qh[o] = h0; Qh[o + 1] = h1;
    Qr[o]     = __float2half(x.x - __half2float(h0));
    Qr[o + 1] = __float2half(x.y - __half2float(h1));
    float s = x.x * x.x + x.y * x.y;
    s += __shfl_xor(s, 32); s += __shfl_xor(s, 16); s += __shfl_xor(s, 8);
    s += __shfl_xor(s, 4);  s += __shfl_xor(s, 2);  s += __shfl_xor(s, 1);
    if (L == 0) qsq[r] = s;
}

__global__ void prep_sam(const float* __restrict__ X, __half* __restrict__ Xsam,
                         float* __restrict__ tsqS) {
    int tid = threadIdx.x;
    int L = tid & 63, wv = tid >> 6;
    int t16 = blockIdx.x * 4 + wv;            // < 512
    int am = L & 15, aq = L >> 4;
    int j = t16 * 16 + am;
    int n = j * SAMP_STRIDE + SAMP_OFF;       // always < N_
    float ssq = 0.f;
    #pragma unroll
    for (int ks = 0; ks < 4; ++ks) {
        int c = ks * 32 + aq * 8;
        float4 a = *(const float4*)(X + (size_t)n * D_ + c);
        float4 b = *(const float4*)(X + (size_t)n * D_ + c + 4);
        half8 h;
        h[0]=(_Float16)a.x; h[1]=(_Float16)a.y; h[2]=(_Float16)a.z; h[3]=(_Float16)a.w;
        h[4]=(_Float16)b.x; h[5]=(_Float16)b.y; h[6]=(_Float16)b.z; h[7]=(_Float16)b.w;
        ssq += a.x*a.x + a.y*a.y + a.z*a.z + a.w*a.w
             + b.x*b.x + b.y*b.y + b.z*b.z + b.w*b.w;
        *(half8*)(Xsam + ((size_t)(t16 * 4 + ks)) * 512 + L * 8) = h;
    }
    ssq += __shfl_xor(ssq, 16); ssq += __shfl_xor(ssq, 32);
    if (aq == 0) tsqS[j] = ssq;
}

// ---------------------------------------------------------- sample_T --------
// QTS=16 queries/block -> 256 blocks (all CUs busy).
__global__ __launch_bounds__(256, 2) void sample_T(
    const __half* __restrict__ Qh, const __half* __restrict__ Qr,
    const __half* __restrict__ Xsam, const float* __restrict__ tsqS,
    const float* __restrict__ qsq, const unsigned* __restrict__ maxXr2,
    float* __restrict__ Teff, float* __restrict__ rawT, float* __restrict__ EwA)
{
    __shared__ float sT[QTS][130];
    const int tid = threadIdx.x, L = tid & 63, wv = tid >> 6;
    const int qbase = blockIdx.x * QTS;
    const int nwv = wv * 64;
    const int am = L & 15, aq = L >> 4;

    half8 afh[4], afr[4];
    #pragma unroll
    for (int ks = 0; ks < 4; ++ks) {
        size_t o = (size_t)(qbase + am) * D_ + ks * 32 + aq * 8;
        afh[ks] = *(const half8*)(Qh + o);
        afr[ks] = *(const half8*)(Qr + o);
    }
    const half8* sp = (const half8*)Xsam;

    float t2a[4], t2b[4];
    #pragma unroll
    for (int rg = 0; rg < 4; ++rg) { t2a[rg] = inf_f(); t2b[rg] = inf_f(); }

    #pragma unroll 1
    for (int it = 0; it < SAMP_ITERS; ++it) {
        const int nbase = it * BN;
        const size_t segb = (size_t)((nbase + nwv) >> 4) * 4;
        floatx4 acc[4] = {};
        #pragma unroll
        for (int ks = 0; ks < 4; ++ks) {
            half8 bf[4];
            #pragma unroll
            for (int nt = 0; nt < 4; ++nt)
                bf[nt] = sp[(segb + nt * 4 + ks) * 64 + L];
            #pragma unroll
            for (int nt = 0; nt < 4; ++nt) {
                acc[nt] = __builtin_amdgcn_mfma_f32_16x16x32_f16(
                    afh[ks], bf[nt], acc[nt], 0, 0, 0);
                acc[nt] = __builtin_amdgcn_mfma_f32_16x16x32_f16(
                    afr[ks], bf[nt], acc[nt], 0, 0, 0);
            }
        }
        float ts[4];
        #pragma unroll
        for (int nt = 0; nt < 4; ++nt)
            ts[nt] = tsqS[nbase + nwv + nt * 16 + am];
        #pragma unroll
        for (int rg = 0; rg < 4; ++rg) {
            float m1 = t2a[rg], m2 = t2b[rg];
            #pragma unroll
            for (int nt = 0; nt < 4; ++nt) {
                float v = ts[nt] - 2.f * acc[nt][rg];
                if (v < m2) { if (v < m1) { m2 = m1; m1 = v; } else m2 = v; }
            }
            t2a[rg] = m1; t2b[rg] = m2;
        }
    }
    #pragma unroll
    for (int rg = 0; rg < 4; ++rg) {
        int q = aq * 4 + rg;
        sT[q][wv * 32 + am * 2 + 0] = t2a[rg];
        sT[q][wv * 32 + am * 2 + 1] = t2b[rg];
    }
    __syncthreads();

    #pragma unroll 1
    for (int j = 0; j < 4; ++j) {
        int q = wv * 4 + j;
        float a = sT[q][2 * L], b = sT[q][2 * L + 1];
        float g = 0.f;
        #pragma unroll 1
        for (int r = 0; r < 16; ++r) {
            float mn = fminf(a, b);
            mn = fminf(mn, __shfl_xor(mn, 32)); mn = fminf(mn, __shfl_xor(mn, 16));
            mn = fminf(mn, __shfl_xor(mn, 8));  mn = fminf(mn, __shfl_xor(mn, 4));
            mn = fminf(mn, __shfl_xor(mn, 2));  mn = fminf(mn, __shfl_xor(mn, 1));
            g = mn;
            ull ba = __ballot(a == g);
            if (ba) { if (L == __ffsll(ba) - 1) a = inf_f(); }
            else    { ull bb = __ballot(b == g); if (L == __ffsll(bb) - 1) b = inf_f(); }
        }
        if (L == 0) {
            int gq = qbase + q;
            float e = 2.f * sqrtf(qsq[gq]) * sqrtf(__uint_as_float(*maxXr2)) + 0.02f;
            rawT[gq] = g; EwA[gq] = e; Teff[gq] = g + e;
        }
    }
}

// ------------------------------------------------------------- main ---------
__global__ __launch_bounds__(256, 4) void knn_main(
    const __half* __restrict__ Qh, const __half* __restrict__ Qr,
    const __half* __restrict__ Xs, const float* __restrict__ tsq,
    const float* __restrict__ Teff, ull* __restrict__ candG,
    int* __restrict__ cntC, int* __restrict__ flagF)
{
    __shared__ ull candL[QT][CW];                 // 12 KB
    __shared__ int cntL[QT];

    const int tid = threadIdx.x, L = tid & 63, wv = tid >> 6;
    const int lb = blockIdx.x, ch = lb & (NCH - 1);   // XCD = lb & 7
    const int qbase = (lb >> 4) * QT, chBase = ch * CHUNK, nwv = wv * 64;
    const int am = L & 15, aq = L >> 4;

    if (tid < QT) cntL[tid] = 0;
    __syncthreads();                              // barrier #1

    float th[2][4];
    #pragma unroll
    for (int qt = 0; qt < 2; ++qt)
        #pragma unroll
        for (int rg = 0; rg < 4; ++rg)
            th[qt][rg] = Teff[qbase + qt * 16 + aq * 4 + rg];

    half8 afh[2][4], afr[2][4];
    #pragma unroll
    for (int qt = 0; qt < 2; ++qt)
        #pragma unroll
        for (int ks = 0; ks < 4; ++ks) {
            size_t o = (size_t)(qbase + qt * 16 + am) * D_ + ks * 32 + aq * 8;
            afh[qt][ks] = *(const half8*)(Qh + o);
            afr[qt][ks] = *(const half8*)(Qr + o);
        }
    const half8* sp = (const half8*)Xs;

    // preload iter0 ks0 B-fragments
    half8 bc[4], bn[4];
    {
        size_t s0 = (size_t)((chBase + nwv) >> 4) * 4;
        #pragma unroll
        for (int nt = 0; nt < 4; ++nt)
            bc[nt] = sp[(s0 + nt * 4) * 64 + L];
    }

    #pragma unroll 1
    for (int it = 0; it < ITERS; ++it) {
        const int nbase = chBase + it * BN;
        const size_t sg  = (size_t)((nbase + nwv) >> 4) * 4;
        const size_t sgN = sg + (BN >> 4) * 4;    // next iter's base seg
        float ts[4];
        #pragma unroll
        for (int nt = 0; nt < 4; ++nt)
            ts[nt] = tsq[nbase + nwv + nt * 16 + am];

        floatx4 acc[2][4] = {};
        #pragma unroll
        for (int ks = 0; ks < 4; ++ks) {
            const bool hasNext = (ks < 3) || (it + 1 < ITERS);
            if (hasNext) {
                const size_t sb = (ks < 3) ? (sg + ks + 1) : sgN;
                #pragma unroll
                for (int nt = 0; nt < 4; ++nt)
                    bn[nt] = sp[(sb + nt * 4) * 64 + L];
            }
            #pragma unroll
            for (int nt = 0; nt < 4; ++nt)
                #pragma unroll
                for (int qt = 0; qt < 2; ++qt) {
                    acc[qt][nt] = __builtin_amdgcn_mfma_f32_16x16x32_f16(
                        afh[qt][ks], bc[nt], acc[qt][nt], 0, 0, 0);
                    acc[qt][nt] = __builtin_amdgcn_mfma_f32_16x16x32_f16(
                        afr[qt][ks], bc[nt], acc[qt][nt], 0, 0, 0);
                }
            if (hasNext) {
                #pragma unroll
                for (int nt = 0; nt < 4; ++nt) bc[nt] = bn[nt];
            }
        }

        // scores in place: s = tsq[n] - 2*dot  (C: row=q, col=n)
        #pragma unroll
        for (int qt = 0; qt < 2; ++qt)
            #pragma unroll
            for (int nt = 0; nt < 4; ++nt)
                acc[qt][nt] = ts[nt] - 2.f * acc[qt][nt];

        unsigned need = 0;
        #pragma unroll
        for (int qt = 0; qt < 2; ++qt)
            #pragma unroll
            for (int nt = 0; nt < 4; ++nt)
                #pragma unroll
                for (int rg = 0; rg < 4; ++rg)
                    if (acc[qt][nt][rg] < th[qt][rg])
                        need |= 1u << (qt * 16 + nt * 4 + rg);

        if (__any(need != 0)) {
            #pragma unroll
            for (int qt = 0; qt < 2; ++qt) {
                if (!__any((need >> (qt * 16)) & 0xffffu)) continue;
                #pragma unroll
                for (int nt = 0; nt < 4; ++nt) {
                    if (!__any((need >> (qt * 16 + nt * 4)) & 0xfu)) continue;
                    #pragma unroll
                    for (int rg = 0; rg < 4; ++rg) {
                        unsigned b = 1u << (qt * 16 + nt * 4 + rg);
                        if (need & b) {
                            int q = qt * 16 + aq * 4 + rg;
                            int pos = atomicAdd(&cntL[q], 1);   // LDS atomic
                            if (pos < CW)
                                candL[q][pos] = pack_cand(acc[qt][nt][rg],
                                    (unsigned)(nbase + nwv + nt * 16 + am));
                            else
                                flagF[qbase + q] = 1;           // ~never
                        }
                    }
                }
            }
        }
    }

    __syncthreads();                              // barrier #2 (pre-dump)

    // dump per-(query,chunk) lists to fixed global slots (no atomics)
    #pragma unroll 1
    for (int q8 = 0; q8 < 8; ++q8) {
        int q = wv * 8 + q8;
        int gq = qbase + q;
        int c = cntL[q];
        int cc = c < CW ? c : CW;
        if (L < cc)
            candG[((size_t)gq * NCH + ch) * CW + L] = candL[q][L];
        if (L == 0)
            cntC[gq * NCH + ch] = cc;
    }
}

// ------------------------------------------------------------ finalize ------
__global__ void finalize(const ull* __restrict__ candG, const int* __restrict__ cntC,
                         int* __restrict__ flagF, const float* __restrict__ Qm,
                         const float* __restrict__ X, const float* __restrict__ tsq,
                         const float* __restrict__ rawT, const float* __restrict__ EwA,
                         const float* __restrict__ Ytr, float* __restrict__ out)
{
    int L = threadIdx.x & 63;
    int q = blockIdx.x * 4 + (threadIdx.x >> 6);
    if (flagF[q]) return;                       // fallback handles
    int cg = (L < NCH) ? cntC[q * NCH + L] : 0;
    int ctot = cg;
    ctot += __shfl_xor(ctot, 32); ctot += __shfl_xor(ctot, 16);
    ctot += __shfl_xor(ctot, 8);  ctot += __shfl_xor(ctot, 4);
    ctot += __shfl_xor(ctot, 2);  ctot += __shfl_xor(ctot, 1);
    if (ctot < K_) { if (L == 0) flagF[q] = 1; return; }

    // merge 16 sorted-by-sort lists -> global top-64 by approx (ascending)
    ull s = DEADC;
    #pragma unroll 1
    for (int g = 0; g < NCH; ++g) {
        int c_g = __shfl(cg, g);
        if (c_g == 0) continue;
        ull v = (L < c_g) ? candG[((size_t)q * NCH + g) * CW + L] : DEADC;
        v = bitonic64(v, L);
        ull w = __shfl(v, 63 - L);
        s = bimerge64(u64min(s, w), L);
    }

    int cr = ctot < 64 ? ctot : 64;
    unsigned n = (unsigned)(s & 0xffffffffu);
    ull pe = DEADC;
    if (L < cr) {
        const float4* xp = (const float4*)(X + (size_t)n * D_);
        const float4* qp = (const float4*)(Qm + (size_t)q * D_);
        float d = 0.f;
        #pragma unroll 8
        for (int i = 0; i < 32; ++i) {
            float4 xv = xp[i], qv = qp[i];
            d += qv.x * xv.x + qv.y * xv.y + qv.z * xv.z + qv.w * xv.w;
        }
        pe = pack_cand(tsq[n] - 2.f * d, n);
    }
    ull pe2 = bitonic64(pe, L);
    float exact31 = unpack_score(__shfl(pe2, K_ - 1));
    bool ok = exact31 < rawT[q];
    if (ctot > 64) {
        float A63 = unpack_score(__shfl(s, 63));
        ok = ok && (A63 - EwA[q] > exact31);
    }
    if (!ok) { if (L == 0) flagF[q] = 1; return; }
    float ys = 0.f;
    if (L < K_) ys = Ytr[(unsigned)(pe2 & 0xffffffffu)];
    ys += __shfl_xor(ys, 32); ys += __shfl_xor(ys, 16); ys += __shfl_xor(ys, 8);
    ys += __shfl_xor(ys, 4);  ys += __shfl_xor(ys, 2);  ys += __shfl_xor(ys, 1);
    if (L == 0) out[q] = ys * (1.f / K_);
}

// ------------------------------------------------------------ fallback ------
__global__ void fallback(const int* __restrict__ flagF, const float* __restrict__ Qm,
                         const float* __restrict__ X, const float* __restrict__ tsq,
                         const float* __restrict__ Ytr, float* __restrict__ out)
{
    int L = threadIdx.x & 63;
    int q = blockIdx.x * 4 + (threadIdx.x >> 6);
    if (!flagF[q]) return;                      // ~never taken
    const float4* qp = (const float4*)(Qm + (size_t)q * D_);
    ull last = 0;
    float ysum = 0.f;
    for (int r = 0; r < K_; ++r) {
        ull best = DEADC;
        for (int j = 0; j < NPAD / 64; ++j) {
            int n = j * 64 + L;
            if (n < N_) {
                const float4* xp = (const float4*)(X + (size_t)n * D_);
                float d = 0.f;
                #pragma unroll 4
                for (int i = 0; i < 32; ++i) {
                    float4 xv = xp[i], qv = qp[i];
                    d += qv.x * xv.x + qv.y * xv.y + qv.z * xv.z + qv.w * xv.w;
                }
                ull k = pack_cand(tsq[n] - 2.f * d, n);
                if (k > last && k < best) best = k;
            }
        }
        best = u64min(best, __shfl_xor(best, 32));
        best = u64min(best, __shfl_xor(best, 16));
        best = u64min(best, __shfl_xor(best, 8));
        best = u64min(best, __shfl_xor(best, 4));
        best = u64min(best, __shfl_xor(best, 2));
        best = u64min(best, __shfl_xor(best, 1));
        if (L == 0) ysum += Ytr[(unsigned)(best & 0xffffffffu)];
        last = best;
    }
    if (L == 0) out[q] = ysum * (1.f / K_);
}

// ------------------------------------------------------------- launch -------
extern "C" void kernel_launch(void* const* d_in, const int* in_sizes, int n_in,
                              void* d_out, int out_size, void* d_ws, size_t ws_size,
                              hipStream_t stream)
{
    const float* Qm  = (const float*)d_in[0];   // [4096,128]
    const float* X   = (const float*)d_in[1];   // [100000,128]
    const float* Ytr = (const float*)d_in[2];   // [100000]
    float* out = (float*)d_out;                 // [4096]

    char* w = (char*)d_ws;
    auto alloc = [&](size_t bytes) {
        char* p = w; w += (bytes + 255) & ~(size_t)255; return p;
    };
    __half* Xs   = (__half*)  alloc((size_t)NPAD * D_ * 2);     // 26.2 MB
    __half* Qh   = (__half*)  alloc((size_t)Q_ * D_ * 2);       // 1 MB
    __half* Qr   = (__half*)  alloc((size_t)Q_ * D_ * 2);       // 1 MB
    float*  ts   = (float*)   alloc((size_t)NPAD * 4);          // 0.41 MB
    __half* Xsm  = (__half*)  alloc((size_t)SAMP_M * D_ * 2);   // 2 MB
    float*  tsS  = (float*)   alloc((size_t)SAMP_M * 4);        // 32 KB
    ull*    cd   = (ull*)     alloc((size_t)Q_ * NCH * CW * 8); // 25.2 MB
    int*    cnC  = (int*)     alloc((size_t)Q_ * NCH * 4);      // 0.26 MB
    int*    flg  = (int*)     alloc((size_t)Q_ * 4);            // 16 KB
    unsigned* mxr= (unsigned*)alloc(256);
    float*  Tef  = (float*)   alloc((size_t)Q_ * 4);
    float*  rwT  = (float*)   alloc((size_t)Q_ * 4);
    float*  Ew   = (float*)   alloc((size_t)Q_ * 4);
    float*  qs   = (float*)   alloc((size_t)Q_ * 4);            // total ~56.4 MB

    // zero flags + maxXr2 (contiguous, 256-aligned allocs)
    hipMemsetAsync(flg, 0, (size_t)Q_ * 4 + 256, stream);

    prep_xs <<<NPAD / 64,    256, 0, stream>>>(X, Xs, ts, mxr);
    prep_q  <<<Q_ / 4,       256, 0, stream>>>(Qm, Qh, Qr, qs);
    prep_sam<<<SAMP_M / 64,  256, 0, stream>>>(X, Xsm, tsS);
    sample_T<<<Q_ / QTS,     256, 0, stream>>>(Qh, Qr, Xsm, tsS, qs, mxr, Tef, rwT, Ew);
    knn_main<<<(Q_ / QT) * NCH, 256, 0, stream>>>(Qh, Qr, Xs, ts, Tef, cd, cnC, flg);
    finalize<<<Q_ / 4,       256, 0, stream>>>(cd, cnC, flg, Qm, X, ts, rwT, Ew, Ytr, out);
    fallback<<<Q_ / 4,       256, 0, stream>>>(flg, Qm, X, ts, Ytr, out);
}